// Round 14
// baseline (386.544 us; speedup 1.0000x reference)
//
#include <hip/hip_runtime.h>

typedef __attribute__((ext_vector_type(8))) __bf16 bf16x8;
typedef __attribute__((ext_vector_type(8))) unsigned short us8;
typedef __attribute__((ext_vector_type(4))) float f32x4;

#define NB 16
#define B_TOTAL 131072
#define SST 36            // nq s-stride (floats)
#define BST 580           // nq b-stride (floats) = 16*36+4

__device__ __forceinline__ unsigned short f2bf(float f) {
  union { float f; unsigned int u; } c; c.f = f;
  unsigned int u = c.u;
  u += 0x7fffu + ((u >> 16) & 1u);   // RNE
  return (unsigned short)(u >> 16);
}
__device__ __forceinline__ bf16x8 as_bf(us8 v) {
  union { us8 u; bf16x8 b; } c; c.u = v; return c.b;
}
// 0.1 * tanh(x), fast: 0.1 - 0.2/(e^{2x}+1); rcp-based divide (err ~2^-21)
// inf-safe: x large -> 0.1 ; x very negative -> -0.1
__device__ __forceinline__ float tanh01(float x) {
  float t = __expf(2.0f * x);
  return 0.1f - __fdividef(0.2f, t + 1.0f);
}

// ---------------- main kernel: 512 threads = 16 batch rows ----------------
// No workspace: all weight fragments are built in-kernel from raw qw/rw/tau.
// fragment layouts (per wave, per s, per kh), identical to the old prep kernel:
//   rw  frag: lane holds rw[h0+e][k][s],  h0=(lane>>4)*8, k=kh*16+(lane&15)
//   qw  frag: lanes<16 hold qw[e][kh*16+lane][s]; other lanes zero
//   diag frag: lane holds (h0+e==k) ? bf16(1-0.1/tau[k]) : 0
__global__ __launch_bounds__(512, 2) void shq_main(
    const float* __restrict__ x, const float* __restrict__ hq_g,
    const float* __restrict__ syn, const float* __restrict__ corr,
    const float* __restrict__ qw_g, const float* __restrict__ rw_g,
    const float* __restrict__ tau_g,
    float* __restrict__ out) {
  // Time-multiplexed buffer:
  //   [barA, barB): hqT bf16 [s][b][h], strides s:640, b:40 shorts (20.5 KB)
  //   [barB, end):  nq   f32 [b][s][h], strides b:BST, s:SST floats (37.1 KB)
  __shared__ float smem[16 * BST];
  __shared__ float2 lds_pi[NB * 16];   // (prob, inv_norm) per (b,s)
  unsigned short* hqT = (unsigned short*)smem;

  const int tid = threadIdx.x;
  const int b0 = blockIdx.x * NB;
  const int lane = tid & 63;
  const int w = tid >> 6;     // wave id: owns s = 2w, 2w+1
  const int kb = lane & 15;   // fragment column
  const int h0 = (lane >> 4) * 8;

  us8 z8 = {0, 0, 0, 0, 0, 0, 0, 0};

  // ---- prologue: x row (bf16 A-frag) + diag fragments from tau ----
  us8 xu = z8;
  if (lane < 16) {
    const float* xb = x + (size_t)(b0 + lane) * 8;
    f32x4 a = *(const f32x4*)xb, b = *(const f32x4*)(xb + 4);
    xu[0] = f2bf(a[0]); xu[1] = f2bf(a[1]); xu[2] = f2bf(a[2]); xu[3] = f2bf(a[3]);
    xu[4] = f2bf(b[0]); xu[5] = f2bf(b[1]); xu[6] = f2bf(b[2]); xu[7] = f2bf(b[3]);
  }
  us8 dg0 = z8, dg1 = z8;
  {
    const int k0 = kb, k1 = 16 + kb;
    unsigned short v0 = f2bf(1.0f - 0.1f / tau_g[k0]);
    unsigned short v1 = f2bf(1.0f - 0.1f / tau_g[k1]);
#pragma unroll
    for (int e = 0; e < 8; ++e) {
      dg0[e] = (h0 + e == k0) ? v0 : (unsigned short)0;
      dg1[e] = (h0 + e == k1) ? v1 : (unsigned short)0;
    }
  }

  // ---- phase 1: thread=(bl,h): syndrome -> mask -> correction -> hqT ----
  {
    const int bl = tid >> 5, hh = tid & 31;
    const float* hb = hq_g + (((size_t)(b0 + bl) * 32) + hh) * 16;
    f32x4 h0v = *(const f32x4*)(hb), h1v = *(const f32x4*)(hb + 4);
    f32x4 h2v = *(const f32x4*)(hb + 8), h3v = *(const f32x4*)(hb + 12);
    float hrow[16];
#pragma unroll
    for (int q = 0; q < 4; ++q) {
      hrow[0 + q] = h0v[q]; hrow[4 + q] = h1v[q]; hrow[8 + q] = h2v[q]; hrow[12 + q] = h3v[q];
    }
    float sd[4];
#pragma unroll
    for (int c = 0; c < 4; ++c) {
      float a = 0.f;
#pragma unroll
      for (int s = 0; s < 16; ++s) a = fmaf(hrow[s], syn[c * 16 + s], a);
      sd[c] = (fabsf(a) > 0.01f) ? a : 0.f;
    }
#pragma unroll
    for (int s = 0; s < 16; ++s) {
      float cs = sd[0] * corr[s] + sd[1] * corr[16 + s] + sd[2] * corr[32 + s] + sd[3] * corr[48 + s];
      hqT[s * 640 + bl * 40 + hh] = f2bf(hrow[s] - cs);
    }
  }
  __syncthreads();   // A: hqT ready

  // ---- phase 2a: pull A-frags (hq) out of hqT before it is clobbered ----
  us8 hq_u[2];
#pragma unroll
  for (int sl = 0; sl < 2; ++sl)
    hq_u[sl] = *(const us8*)&hqT[(2 * w + sl) * 640 + (lane & 15) * 40 + (lane >> 4) * 8];
  __syncthreads();   // B: hqT dead, nq region free

  // ---- phase 2b: MFMA rec+inp+decay per (s, khalf); write new_q f32 ----
  {
    f32x4 zro = {0.f, 0.f, 0.f, 0.f};
#pragma unroll
    for (int sl = 0; sl < 2; ++sl) {
      int s = 2 * w + sl;
      // build rw fragments: rw[h0+e][k][s], addr = ((h0+e)*32+k)*16+s, e-stride 512
      us8 rw0, rw1;
      {
        const float* rp = rw_g + ((size_t)h0 * 32 + kb) * 16 + s;   // kh=0
#pragma unroll
        for (int e = 0; e < 8; ++e) {
          rw0[e] = f2bf(rp[e * 512]);
          rw1[e] = f2bf(rp[e * 512 + 256]);   // kh=1: k += 16 -> +256 floats
        }
      }
      // build qw fragments (lanes<16): qw[e][kh*16+lane][s], addr = e*512 + kh*256 + lane*16 + s
      us8 qw0 = z8, qw1 = z8;
      if (lane < 16) {
        const float* qp = qw_g + lane * 16 + s;
#pragma unroll
        for (int e = 0; e < 8; ++e) {
          qw0[e] = f2bf(qp[e * 512]);
          qw1[e] = f2bf(qp[e * 512 + 256]);
        }
      }
      bf16x8 hqf = as_bf(hq_u[sl]);
#pragma unroll
      for (int kh = 0; kh < 2; ++kh) {
        f32x4 acc = __builtin_amdgcn_mfma_f32_16x16x32_bf16(as_bf(xu), as_bf(kh ? qw1 : qw0), zro, 0, 0, 0);
        acc = __builtin_amdgcn_mfma_f32_16x16x32_bf16(hqf, as_bf(kh ? rw1 : rw0), acc, 0, 0, 0);
        f32x4 na;
#pragma unroll
        for (int r = 0; r < 4; ++r) na[r] = tanh01(acc[r]);
        na = __builtin_amdgcn_mfma_f32_16x16x32_bf16(hqf, as_bf(kh ? dg1 : dg0), na, 0, 0, 0);
        int k = kh * 16 + (lane & 15);
#pragma unroll
        for (int r = 0; r < 4; ++r) {
          int br = (lane >> 4) * 4 + r;
          smem[br * BST + s * SST + k] = na[r];
        }
      }
    }
  }
  __syncthreads();   // C: nq ready

  // ---- phase 3a: thread=(b,s,half): stream stable, reduce norms, write pi ----
  {
    int b3 = tid >> 5, idx = tid & 31;
    int s3 = idx >> 1, half = idx & 1;
    int base = b3 * BST + s3 * SST + half * 16;
    float ssq = 0.f, sab = 0.f;
    f32x4 zv = {0.f, 0.f, 0.f, 0.f};
#pragma unroll
    for (int q = 0; q < 4; ++q) {
      f32x4 c0 = *(const f32x4*)&smem[base + 4 * q];
      f32x4 cm = (s3 > 0)  ? *(const f32x4*)&smem[base - SST + 4 * q] : zv;
      f32x4 cp = (s3 < 15) ? *(const f32x4*)&smem[base + SST + 4 * q] : zv;
#pragma unroll
      for (int e = 0; e < 4; ++e) {
        float st = fmaf(0.04f * c0[e], cm[e] + cp[e], c0[e]);
        ssq = fmaf(st, st, ssq);
        sab += fabsf(st);
      }
    }
    ssq += __shfl_xor(ssq, 1);
    sab += __shfl_xor(sab, 1);
    float inv = __fdividef(1.0f, sqrtf(ssq) + 1e-8f);
    float energy = ssq * inv * inv;
    float mag = sab * inv;
    float pu = __fdividef(mag, energy + 1e-6f);
    float psum = pu;
#pragma unroll
    for (int m = 2; m < 32; m <<= 1) psum += __shfl_xor(psum, m);
    if (half == 0) {
      float2 pv = {__fdividef(pu, psum), inv};
      lds_pi[b3 * 16 + s3] = pv;
    }
  }
  __syncthreads();   // D: pi ready (nq untouched)

  // ---- phase 3b: thread=(b,h): streaming stable column, q_norm + output ----
  {
    const int b3 = tid >> 5, h3 = tid & 31;
    const float* colp = smem + b3 * BST + h3;
    float* qp = out + 4194304 + (((size_t)(b0 + b3) * 32) + h3) * 16;
    float prev = 0.f;
    float cur = colp[0];
    float oacc = 0.f;
    f32x4 qbuf;
#pragma unroll
    for (int s = 0; s < 16; ++s) {
      float nxt = (s < 15) ? colp[(s + 1) * SST] : 0.f;
      float st = fmaf(0.04f * cur, prev + nxt, cur);
      float2 pv = lds_pi[b3 * 16 + s];
      float q = st * pv.y;
      qbuf[s & 3] = q;
      oacc = fmaf(q, pv.x, oacc);
      if ((s & 3) == 3) *(f32x4*)(qp + (s - 3)) = qbuf;
      prev = cur; cur = nxt;
    }
    out[(size_t)(b0 + b3) * 32 + h3] = oacc;
  }
}

extern "C" void kernel_launch(void* const* d_in, const int* in_sizes, int n_in,
                              void* d_out, int out_size, void* d_ws, size_t ws_size,
                              hipStream_t stream) {
  const float* x    = (const float*)d_in[0];
  const float* hq   = (const float*)d_in[1];
  const float* qw   = (const float*)d_in[2];
  const float* rw   = (const float*)d_in[3];
  const float* tau  = (const float*)d_in[4];
  const float* syn  = (const float*)d_in[5];
  const float* corr = (const float*)d_in[6];
  (void)d_ws; (void)ws_size;   // workspace deliberately unused
  shq_main<<<B_TOTAL / NB, 512, 0, stream>>>(x, hq, syn, corr, qw, rw, tau, (float*)d_out);
}

// Round 15
// 199.343 us; speedup vs baseline: 1.9391x; 1.9391x over previous
//
#include <hip/hip_runtime.h>

typedef __attribute__((ext_vector_type(8))) __bf16 bf16x8;
typedef __attribute__((ext_vector_type(8))) unsigned short us8;
typedef __attribute__((ext_vector_type(4))) float f32x4;

#define NB 16
#define B_TOTAL 131072
#define SST 36            // nq s-stride (floats)
#define BST 580           // nq b-stride (floats) = 16*36+4

__device__ __forceinline__ unsigned short f2bf(float f) {
  union { float f; unsigned int u; } c; c.f = f;
  unsigned int u = c.u;
  u += 0x7fffu + ((u >> 16) & 1u);   // RNE
  return (unsigned short)(u >> 16);
}
__device__ __forceinline__ bf16x8 as_bf(us8 v) {
  union { us8 u; bf16x8 b; } c; c.u = v; return c.b;
}
// 0.1 * tanh(x), fast: 0.1 - 0.2/(e^{2x}+1); rcp-based divide (err ~2^-21)
// inf-safe: x large -> 0.1 ; x very negative -> -0.1
__device__ __forceinline__ float tanh01(float x) {
  float t = __expf(2.0f * x);
  return 0.1f - __fdividef(0.2f, t + 1.0f);
}
// load us8 from 3 redundant copies (stride st shorts), per-dword majority vote:
// r = (a==b) ? a : c.  st==0 degenerates to a plain load.
__device__ __forceinline__ us8 ld3(const unsigned short* p, int st) {
  union { us8 v; unsigned int d[4]; } ua, ub, uc, ur;
  ua.v = *(const us8*)(p);
  ub.v = *(const us8*)(p + st);
  uc.v = *(const us8*)(p + 2 * st);
#pragma unroll
  for (int i = 0; i < 4; ++i) ur.d[i] = (ua.d[i] == ub.d[i]) ? ua.d[i] : uc.d[i];
  return ur.v;
}

// ---------------- prep: pre-arrange B-fragments (bf16) into ws, 3 copies -------
__global__ void shq_prep(const float* __restrict__ qw, const float* __restrict__ rw,
                         const float* __restrict__ tau,
                         unsigned short* __restrict__ rwfrag,
                         unsigned short* __restrict__ qwfrag,
                         unsigned short* __restrict__ dgfrag, int st) {
  int g = blockIdx.x * 256 + threadIdx.x;
  if (g < 2048) {                       // 16 s * 2 kh * 64 lanes
    int s = g >> 7, kh = (g >> 6) & 1, ln = g & 63;
    int k = kh * 16 + (ln & 15), h0 = (ln >> 4) * 8;
    us8 v;
#pragma unroll
    for (int e = 0; e < 8; ++e) v[e] = f2bf(rw[((h0 + e) * 32 + k) * 16 + s]);
    unsigned short* d = rwfrag + g * 8;
    *(us8*)(d) = v; *(us8*)(d + st) = v; *(us8*)(d + 2 * st) = v;
  } else if (g < 2560) {                // 16 s * 2 kh * 16 lanes
    int j = g - 2048;
    int s = j >> 5, kh = (j >> 4) & 1, ln = j & 15;
    int hc = kh * 16 + ln;
    us8 v;
#pragma unroll
    for (int e = 0; e < 8; ++e) v[e] = f2bf(qw[(e * 32 + hc) * 16 + s]);
    unsigned short* d = qwfrag + j * 8;
    *(us8*)(d) = v; *(us8*)(d + st) = v; *(us8*)(d + 2 * st) = v;
  } else if (g < 2688) {                // 2 kh * 64 lanes
    int j = g - 2560;
    int kh = (j >> 6) & 1, ln = j & 63;
    int k = kh * 16 + (ln & 15), h0 = (ln >> 4) * 8;
    unsigned short ab = f2bf(1.0f - 0.1f / tau[k]);
    us8 v;
#pragma unroll
    for (int e = 0; e < 8; ++e) v[e] = (h0 + e == k) ? ab : (unsigned short)0;
    unsigned short* d = dgfrag + j * 8;
    *(us8*)(d) = v; *(us8*)(d + st) = v; *(us8*)(d + 2 * st) = v;
  }
}

// ---------------- main kernel: 512 threads = 16 batch rows ----------------
__global__ __launch_bounds__(512, 2) void shq_main(
    const float* __restrict__ x, const float* __restrict__ hq_g,
    const float* __restrict__ syn, const float* __restrict__ corr,
    const unsigned short* __restrict__ rwfrag,
    const unsigned short* __restrict__ qwfrag,
    const unsigned short* __restrict__ dgfrag,
    float* __restrict__ out, int st) {
  // Time-multiplexed buffer:
  //   [barA, barB): hqT bf16 [s][b][h], strides s:640, b:40 shorts (20.5 KB)
  //   [barB, end):  nq   f32 [b][s][h], strides b:BST, s:SST floats (37.1 KB)
  __shared__ float smem[16 * BST];
  __shared__ float2 lds_pi[NB * 16];   // (prob, inv_norm) per (b,s)
  unsigned short* hqT = (unsigned short*)smem;

  const int tid = threadIdx.x;
  const int b0 = blockIdx.x * NB;
  const int lane = tid & 63;
  const int w = tid >> 6;     // wave id: owns s = 2w, 2w+1

  us8 z8 = {0, 0, 0, 0, 0, 0, 0, 0};

  // ---- prologue: x row (bf16 A-frag) ----
  us8 xu = z8;
  if (lane < 16) {
    const float* xb = x + (size_t)(b0 + lane) * 8;
    f32x4 a = *(const f32x4*)xb, b = *(const f32x4*)(xb + 4);
    xu[0] = f2bf(a[0]); xu[1] = f2bf(a[1]); xu[2] = f2bf(a[2]); xu[3] = f2bf(a[3]);
    xu[4] = f2bf(b[0]); xu[5] = f2bf(b[1]); xu[6] = f2bf(b[2]); xu[7] = f2bf(b[3]);
  }

  // ---- phase 1: thread=(bl,h): syndrome -> mask -> correction -> hqT ----
  {
    const int bl = tid >> 5, hh = tid & 31;
    const float* hb = hq_g + (((size_t)(b0 + bl) * 32) + hh) * 16;
    f32x4 h0 = *(const f32x4*)(hb), h1 = *(const f32x4*)(hb + 4);
    f32x4 h2 = *(const f32x4*)(hb + 8), h3 = *(const f32x4*)(hb + 12);
    float hrow[16];
#pragma unroll
    for (int q = 0; q < 4; ++q) {
      hrow[0 + q] = h0[q]; hrow[4 + q] = h1[q]; hrow[8 + q] = h2[q]; hrow[12 + q] = h3[q];
    }
    float sd[4];
#pragma unroll
    for (int c = 0; c < 4; ++c) {
      float a = 0.f;
#pragma unroll
      for (int s = 0; s < 16; ++s) a = fmaf(hrow[s], syn[c * 16 + s], a);
      sd[c] = (fabsf(a) > 0.01f) ? a : 0.f;
    }
#pragma unroll
    for (int s = 0; s < 16; ++s) {
      float cs = sd[0] * corr[s] + sd[1] * corr[16 + s] + sd[2] * corr[32 + s] + sd[3] * corr[48 + s];
      hqT[s * 640 + bl * 40 + hh] = f2bf(hrow[s] - cs);
    }
  }
  __syncthreads();   // A: hqT ready

  // ---- phase 2a: pull A-frags (hq) out of hqT before it is clobbered ----
  us8 hq_u[2];
#pragma unroll
  for (int sl = 0; sl < 2; ++sl)
    hq_u[sl] = *(const us8*)&hqT[(2 * w + sl) * 640 + (lane & 15) * 40 + (lane >> 4) * 8];
  us8 dg0 = ld3(dgfrag + lane * 8, st);
  us8 dg1 = ld3(dgfrag + (64 + lane) * 8, st);
  __syncthreads();   // B: hqT dead, nq region free

  // ---- phase 2b: MFMA rec+inp+decay per (s, khalf); write new_q f32 ----
  {
    f32x4 zro = {0.f, 0.f, 0.f, 0.f};
#pragma unroll
    for (int sl = 0; sl < 2; ++sl) {
      int s = 2 * w + sl;
      us8 rw0 = ld3(rwfrag + ((s * 2 + 0) * 64 + lane) * 8, st);
      us8 rw1 = ld3(rwfrag + ((s * 2 + 1) * 64 + lane) * 8, st);
      us8 qw0 = (lane < 16) ? ld3(qwfrag + ((s * 2 + 0) * 16 + lane) * 8, st) : z8;
      us8 qw1 = (lane < 16) ? ld3(qwfrag + ((s * 2 + 1) * 16 + lane) * 8, st) : z8;
      bf16x8 hqf = as_bf(hq_u[sl]);
#pragma unroll
      for (int kh = 0; kh < 2; ++kh) {
        f32x4 acc = __builtin_amdgcn_mfma_f32_16x16x32_bf16(as_bf(xu), as_bf(kh ? qw1 : qw0), zro, 0, 0, 0);
        acc = __builtin_amdgcn_mfma_f32_16x16x32_bf16(hqf, as_bf(kh ? rw1 : rw0), acc, 0, 0, 0);
        f32x4 na;
#pragma unroll
        for (int r = 0; r < 4; ++r) na[r] = tanh01(acc[r]);
        na = __builtin_amdgcn_mfma_f32_16x16x32_bf16(hqf, as_bf(kh ? dg1 : dg0), na, 0, 0, 0);
        int k = kh * 16 + (lane & 15);
#pragma unroll
        for (int r = 0; r < 4; ++r) {
          int br = (lane >> 4) * 4 + r;
          smem[br * BST + s * SST + k] = na[r];
        }
      }
    }
  }
  __syncthreads();   // C: nq ready

  // ---- phase 3a: thread=(b,s,half): stream stable, reduce norms, write pi ----
  {
    int b3 = tid >> 5, idx = tid & 31;
    int s3 = idx >> 1, half = idx & 1;
    int base = b3 * BST + s3 * SST + half * 16;
    float ssq = 0.f, sab = 0.f;
    f32x4 zv = {0.f, 0.f, 0.f, 0.f};
#pragma unroll
    for (int q = 0; q < 4; ++q) {
      f32x4 c0 = *(const f32x4*)&smem[base + 4 * q];
      f32x4 cm = (s3 > 0)  ? *(const f32x4*)&smem[base - SST + 4 * q] : zv;
      f32x4 cp = (s3 < 15) ? *(const f32x4*)&smem[base + SST + 4 * q] : zv;
#pragma unroll
      for (int e = 0; e < 4; ++e) {
        float st2 = fmaf(0.04f * c0[e], cm[e] + cp[e], c0[e]);
        ssq = fmaf(st2, st2, ssq);
        sab += fabsf(st2);
      }
    }
    ssq += __shfl_xor(ssq, 1);
    sab += __shfl_xor(sab, 1);
    float inv = __fdividef(1.0f, sqrtf(ssq) + 1e-8f);
    float energy = ssq * inv * inv;
    float mag = sab * inv;
    float pu = __fdividef(mag, energy + 1e-6f);
    float psum = pu;
#pragma unroll
    for (int m = 2; m < 32; m <<= 1) psum += __shfl_xor(psum, m);
    if (half == 0) {
      float2 pv = {__fdividef(pu, psum), inv};
      lds_pi[b3 * 16 + s3] = pv;
    }
  }
  __syncthreads();   // D: pi ready (nq untouched)

  // ---- phase 3b: thread=(b,h): streaming stable column, q_norm + output ----
  {
    const int b3 = tid >> 5, h3 = tid & 31;
    const float* colp = smem + b3 * BST + h3;
    float* qp = out + 4194304 + (((size_t)(b0 + b3) * 32) + h3) * 16;
    float prev = 0.f;
    float cur = colp[0];
    float oacc = 0.f;
    f32x4 qbuf;
#pragma unroll
    for (int s = 0; s < 16; ++s) {
      float nxt = (s < 15) ? colp[(s + 1) * SST] : 0.f;
      float st2 = fmaf(0.04f * cur, prev + nxt, cur);
      float2 pv = lds_pi[b3 * 16 + s];
      float q = st2 * pv.y;
      qbuf[s & 3] = q;
      oacc = fmaf(q, pv.x, oacc);
      if ((s & 3) == 3) *(f32x4*)(qp + (s - 3)) = qbuf;
      prev = cur; cur = nxt;
    }
    out[(size_t)(b0 + b3) * 32 + h3] = oacc;
  }
}

extern "C" void kernel_launch(void* const* d_in, const int* in_sizes, int n_in,
                              void* d_out, int out_size, void* d_ws, size_t ws_size,
                              hipStream_t stream) {
  const float* x    = (const float*)d_in[0];
  const float* hq   = (const float*)d_in[1];
  const float* qw   = (const float*)d_in[2];
  const float* rw   = (const float*)d_in[3];
  const float* tau  = (const float*)d_in[4];
  const float* syn  = (const float*)d_in[5];
  const float* corr = (const float*)d_in[6];
  unsigned short* ws = (unsigned short*)d_ws;
  unsigned short* rwfrag = ws;            // 16384 shorts
  unsigned short* qwfrag = ws + 16384;    // 4096 shorts
  unsigned short* dgfrag = ws + 20480;    // 1024 shorts (block ends at 21504)
  // triple-redundant copies at +st, +2*st shorts (96 KB extra) when ws allows
  const int st = (ws_size >= (size_t)300 * 1024) ? 24576 : 0;
  shq_prep<<<11, 256, 0, stream>>>(qw, rw, tau, rwfrag, qwfrag, dgfrag, st);
  shq_main<<<B_TOTAL / NB, 512, 0, stream>>>(x, hq, syn, corr, rwfrag, qwfrag, dgfrag, (float*)d_out, st);
}

// Round 16
// 172.939 us; speedup vs baseline: 2.2351x; 1.1527x over previous
//
#include <hip/hip_runtime.h>

typedef __attribute__((ext_vector_type(8))) __bf16 bf16x8;
typedef __attribute__((ext_vector_type(8))) unsigned short us8;
typedef __attribute__((ext_vector_type(4))) float f32x4;

#define NB 16
#define B_TOTAL 131072
#define SST 36            // nq s-stride (floats)
#define BST 580           // nq b-stride (floats) = 16*36+4

__device__ __forceinline__ unsigned short f2bf(float f) {
  union { float f; unsigned int u; } c; c.f = f;
  unsigned int u = c.u;
  u += 0x7fffu + ((u >> 16) & 1u);   // RNE
  return (unsigned short)(u >> 16);
}
__device__ __forceinline__ bf16x8 as_bf(us8 v) {
  union { us8 u; bf16x8 b; } c; c.u = v; return c.b;
}
// 0.1 * tanh(x), fast: 0.1 - 0.2/(e^{2x}+1); rcp-based divide (err ~2^-21)
// inf-safe: x large -> 0.1 ; x very negative -> -0.1
__device__ __forceinline__ float tanh01(float x) {
  float t = __expf(2.0f * x);
  return 0.1f - __fdividef(0.2f, t + 1.0f);
}
// redundant load: copies at p, p+st, p+2*st (shorts). Fast path reads 2 copies;
// on any dword mismatch, read 3rd and majority-vote per dword ((a==b)?a:c).
// st==0 degenerates to a plain load (a==b trivially).
__device__ __forceinline__ us8 ld2v(const unsigned short* p, int st) {
  union U { us8 v; unsigned int d[4]; } a, b, c, r;
  a.v = *(const us8*)(p);
  b.v = *(const us8*)(p + st);
  if ((a.d[0] == b.d[0]) & (a.d[1] == b.d[1]) & (a.d[2] == b.d[2]) & (a.d[3] == b.d[3]))
    return a.v;
  c.v = *(const us8*)(p + 2 * st);
#pragma unroll
  for (int i = 0; i < 4; ++i) r.d[i] = (a.d[i] == b.d[i]) ? a.d[i] : c.d[i];
  return r.v;
}

// ------- prep: pre-arrange B-fragments (bf16) into ws; one copy per block ------
// blocks 0..10 write copy 0, 11..21 copy 1, 22..32 copy 2 -> copies flow through
// different XCD L2s, so any single stale/corrupt path damages at most one copy.
__global__ void shq_prep(const float* __restrict__ qw, const float* __restrict__ rw,
                         unsigned short* __restrict__ rwfrag,
                         unsigned short* __restrict__ qwfrag, int st) {
  const int cp = blockIdx.x / 11;                    // copy index 0..2
  const int g = (blockIdx.x % 11) * 256 + threadIdx.x;
  unsigned short* rwd = rwfrag + cp * st;
  unsigned short* qwd = qwfrag + cp * st;
  if (g < 2048) {                       // 16 s * 2 kh * 64 lanes
    int s = g >> 7, kh = (g >> 6) & 1, ln = g & 63;
    int k = kh * 16 + (ln & 15), h0 = (ln >> 4) * 8;
    us8 v;
#pragma unroll
    for (int e = 0; e < 8; ++e) v[e] = f2bf(rw[((h0 + e) * 32 + k) * 16 + s]);
    *(us8*)(rwd + g * 8) = v;
  } else if (g < 2560) {                // 16 s * 2 kh * 16 lanes
    int j = g - 2048;
    int s = j >> 5, kh = (j >> 4) & 1, ln = j & 15;
    int hc = kh * 16 + ln;
    us8 v;
#pragma unroll
    for (int e = 0; e < 8; ++e) v[e] = f2bf(qw[(e * 32 + hc) * 16 + s]);
    *(us8*)(qwd + j * 8) = v;
  }
}

// ---------------- main kernel: 512 threads = 16 batch rows ----------------
__global__ __launch_bounds__(512, 2) void shq_main(
    const float* __restrict__ x, const float* __restrict__ hq_g,
    const float* __restrict__ syn, const float* __restrict__ corr,
    const unsigned short* __restrict__ rwfrag,
    const unsigned short* __restrict__ qwfrag,
    const float* __restrict__ tau_g,
    float* __restrict__ out, int st) {
  // Time-multiplexed buffer:
  //   [barA, barB): hqT bf16 [s][b][h], strides s:640, b:40 shorts (20.5 KB)
  //   [barB, end):  nq   f32 [b][s][h], strides b:BST, s:SST floats (37.1 KB)
  __shared__ float smem[16 * BST];
  __shared__ float2 lds_pi[NB * 16];   // (prob, inv_norm) per (b,s)
  unsigned short* hqT = (unsigned short*)smem;

  const int tid = threadIdx.x;
  const int b0 = blockIdx.x * NB;
  const int lane = tid & 63;
  const int w = tid >> 6;     // wave id: owns s = 2w, 2w+1
  const int kb = lane & 15;
  const int h0g = (lane >> 4) * 8;

  us8 z8 = {0, 0, 0, 0, 0, 0, 0, 0};

  // ---- prologue: x row + voted weight fragments + diag from tau ----
  us8 xu = z8;
  if (lane < 16) {
    const float* xb = x + (size_t)(b0 + lane) * 8;
    f32x4 a = *(const f32x4*)xb, b = *(const f32x4*)(xb + 4);
    xu[0] = f2bf(a[0]); xu[1] = f2bf(a[1]); xu[2] = f2bf(a[2]); xu[3] = f2bf(a[3]);
    xu[4] = f2bf(b[0]); xu[5] = f2bf(b[1]); xu[6] = f2bf(b[2]); xu[7] = f2bf(b[3]);
  }
  us8 rwf[2][2], qwf[2][2];
#pragma unroll
  for (int sl = 0; sl < 2; ++sl)
#pragma unroll
    for (int kh = 0; kh < 2; ++kh) {
      int s = 2 * w + sl;
      rwf[sl][kh] = ld2v(rwfrag + ((s * 2 + kh) * 64 + lane) * 8, st);
      qwf[sl][kh] = (lane < 16) ? ld2v(qwfrag + ((s * 2 + kh) * 16 + lane) * 8, st) : z8;
    }
  us8 dg0 = z8, dg1 = z8;
  {
    unsigned short v0 = f2bf(1.0f - 0.1f / tau_g[kb]);
    unsigned short v1 = f2bf(1.0f - 0.1f / tau_g[16 + kb]);
#pragma unroll
    for (int e = 0; e < 8; ++e) {
      dg0[e] = (h0g + e == kb) ? v0 : (unsigned short)0;
      dg1[e] = (h0g + e == 16 + kb) ? v1 : (unsigned short)0;
    }
  }

  // ---- phase 1: thread=(bl,h): syndrome -> mask -> correction -> hqT ----
  {
    const int bl = tid >> 5, hh = tid & 31;
    const float* hb = hq_g + (((size_t)(b0 + bl) * 32) + hh) * 16;
    f32x4 h0 = *(const f32x4*)(hb), h1 = *(const f32x4*)(hb + 4);
    f32x4 h2 = *(const f32x4*)(hb + 8), h3 = *(const f32x4*)(hb + 12);
    float hrow[16];
#pragma unroll
    for (int q = 0; q < 4; ++q) {
      hrow[0 + q] = h0[q]; hrow[4 + q] = h1[q]; hrow[8 + q] = h2[q]; hrow[12 + q] = h3[q];
    }
    float sd[4];
#pragma unroll
    for (int c = 0; c < 4; ++c) {
      float a = 0.f;
#pragma unroll
      for (int s = 0; s < 16; ++s) a = fmaf(hrow[s], syn[c * 16 + s], a);
      sd[c] = (fabsf(a) > 0.01f) ? a : 0.f;
    }
#pragma unroll
    for (int s = 0; s < 16; ++s) {
      float cs = sd[0] * corr[s] + sd[1] * corr[16 + s] + sd[2] * corr[32 + s] + sd[3] * corr[48 + s];
      hqT[s * 640 + bl * 40 + hh] = f2bf(hrow[s] - cs);
    }
  }
  __syncthreads();   // A: hqT ready

  // ---- phase 2a: pull A-frags (hq) out of hqT before it is clobbered ----
  us8 hq_u[2];
#pragma unroll
  for (int sl = 0; sl < 2; ++sl)
    hq_u[sl] = *(const us8*)&hqT[(2 * w + sl) * 640 + (lane & 15) * 40 + (lane >> 4) * 8];
  __syncthreads();   // B: hqT dead, nq region free

  // ---- phase 2b: MFMA rec+inp+decay per (s, khalf); write new_q f32 ----
  {
    f32x4 zro = {0.f, 0.f, 0.f, 0.f};
#pragma unroll
    for (int sl = 0; sl < 2; ++sl) {
      int s = 2 * w + sl;
      bf16x8 hqf = as_bf(hq_u[sl]);
#pragma unroll
      for (int kh = 0; kh < 2; ++kh) {
        f32x4 acc = __builtin_amdgcn_mfma_f32_16x16x32_bf16(as_bf(xu), as_bf(qwf[sl][kh]), zro, 0, 0, 0);
        acc = __builtin_amdgcn_mfma_f32_16x16x32_bf16(hqf, as_bf(rwf[sl][kh]), acc, 0, 0, 0);
        f32x4 na;
#pragma unroll
        for (int r = 0; r < 4; ++r) na[r] = tanh01(acc[r]);
        na = __builtin_amdgcn_mfma_f32_16x16x32_bf16(hqf, as_bf(kh ? dg1 : dg0), na, 0, 0, 0);
        int k = kh * 16 + (lane & 15);
#pragma unroll
        for (int r = 0; r < 4; ++r) {
          int br = (lane >> 4) * 4 + r;
          smem[br * BST + s * SST + k] = na[r];
        }
      }
    }
  }
  __syncthreads();   // C: nq ready

  // ---- phase 3a: thread=(b,s,half): stream stable, reduce norms, write pi ----
  {
    int b3 = tid >> 5, idx = tid & 31;
    int s3 = idx >> 1, half = idx & 1;
    int base = b3 * BST + s3 * SST + half * 16;
    float ssq = 0.f, sab = 0.f;
    f32x4 zv = {0.f, 0.f, 0.f, 0.f};
#pragma unroll
    for (int q = 0; q < 4; ++q) {
      f32x4 c0 = *(const f32x4*)&smem[base + 4 * q];
      f32x4 cm = (s3 > 0)  ? *(const f32x4*)&smem[base - SST + 4 * q] : zv;
      f32x4 cp = (s3 < 15) ? *(const f32x4*)&smem[base + SST + 4 * q] : zv;
#pragma unroll
      for (int e = 0; e < 4; ++e) {
        float st2 = fmaf(0.04f * c0[e], cm[e] + cp[e], c0[e]);
        ssq = fmaf(st2, st2, ssq);
        sab += fabsf(st2);
      }
    }
    ssq += __shfl_xor(ssq, 1);
    sab += __shfl_xor(sab, 1);
    float inv = __fdividef(1.0f, sqrtf(ssq) + 1e-8f);
    float energy = ssq * inv * inv;
    float mag = sab * inv;
    float pu = __fdividef(mag, energy + 1e-6f);
    float psum = pu;
#pragma unroll
    for (int m = 2; m < 32; m <<= 1) psum += __shfl_xor(psum, m);
    if (half == 0) {
      float2 pv = {__fdividef(pu, psum), inv};
      lds_pi[b3 * 16 + s3] = pv;
    }
  }
  __syncthreads();   // D: pi ready (nq untouched)

  // ---- phase 3b: thread=(b,h): streaming stable column, q_norm + output ----
  {
    const int b3 = tid >> 5, h3 = tid & 31;
    const float* colp = smem + b3 * BST + h3;
    float* qp = out + 4194304 + (((size_t)(b0 + b3) * 32) + h3) * 16;
    float prev = 0.f;
    float cur = colp[0];
    float oacc = 0.f;
    f32x4 qbuf;
#pragma unroll
    for (int s = 0; s < 16; ++s) {
      float nxt = (s < 15) ? colp[(s + 1) * SST] : 0.f;
      float st2 = fmaf(0.04f * cur, prev + nxt, cur);
      float2 pv = lds_pi[b3 * 16 + s];
      float q = st2 * pv.y;
      qbuf[s & 3] = q;
      oacc = fmaf(q, pv.x, oacc);
      if ((s & 3) == 3) *(f32x4*)(qp + (s - 3)) = qbuf;
      prev = cur; cur = nxt;
    }
    out[(size_t)(b0 + b3) * 32 + h3] = oacc;
  }
}

extern "C" void kernel_launch(void* const* d_in, const int* in_sizes, int n_in,
                              void* d_out, int out_size, void* d_ws, size_t ws_size,
                              hipStream_t stream) {
  const float* x    = (const float*)d_in[0];
  const float* hq   = (const float*)d_in[1];
  const float* qw   = (const float*)d_in[2];
  const float* rw   = (const float*)d_in[3];
  const float* tau  = (const float*)d_in[4];
  const float* syn  = (const float*)d_in[5];
  const float* corr = (const float*)d_in[6];
  unsigned short* ws = (unsigned short*)d_ws;
  unsigned short* rwfrag = ws;            // 16384 shorts
  unsigned short* qwfrag = ws + 16384;    // 4096 shorts (block ends at 20480)
  // triple-redundant copies at +st, +2*st shorts when ws allows (graph-safe const)
  const int st = (ws_size >= (size_t)300 * 1024) ? 24576 : 0;
  shq_prep<<<33, 256, 0, stream>>>(qw, rw, rwfrag, qwfrag, st);
  shq_main<<<B_TOTAL / NB, 512, 0, stream>>>(x, hq, syn, corr, rwfrag, qwfrag, tau, (float*)d_out, st);
}

// Round 18
// 172.795 us; speedup vs baseline: 2.2370x; 1.0008x over previous
//
#include <hip/hip_runtime.h>

typedef __attribute__((ext_vector_type(8))) __bf16 bf16x8;
typedef __attribute__((ext_vector_type(8))) unsigned short us8;
typedef __attribute__((ext_vector_type(4))) float f32x4;

#define NB 16
#define B_TOTAL 131072
#define SST 36            // nq s-stride (floats)
#define BST 580           // nq b-stride (floats) = 16*36+4

__device__ __forceinline__ unsigned short f2bf(float f) {
  union { float f; unsigned int u; } c; c.f = f;
  unsigned int u = c.u;
  u += 0x7fffu + ((u >> 16) & 1u);   // RNE
  return (unsigned short)(u >> 16);
}
__device__ __forceinline__ bf16x8 as_bf(us8 v) {
  union { us8 u; bf16x8 b; } c; c.u = v; return c.b;
}
// 0.1 * tanh(x), fast: 0.1 - 0.2/(e^{2x}+1); rcp-based divide (err ~2^-21)
// inf-safe: x large -> 0.1 ; x very negative -> -0.1
__device__ __forceinline__ float tanh01(float x) {
  float t = __expf(2.0f * x);
  return 0.1f - __fdividef(0.2f, t + 1.0f);
}
// redundant load: copies at p, p+st, p+2*st (shorts). Fast path reads 2 copies;
// on any dword mismatch, read 3rd and majority-vote per dword ((a==b)?a:c).
// st==0 degenerates to a plain load (a==b trivially).
__device__ __forceinline__ us8 ld2v(const unsigned short* p, int st) {
  union U { us8 v; unsigned int d[4]; } a, b, c, r;
  a.v = *(const us8*)(p);
  b.v = *(const us8*)(p + st);
  if ((a.d[0] == b.d[0]) & (a.d[1] == b.d[1]) & (a.d[2] == b.d[2]) & (a.d[3] == b.d[3]))
    return a.v;
  c.v = *(const us8*)(p + 2 * st);
#pragma unroll
  for (int i = 0; i < 4; ++i) r.d[i] = (a.d[i] == b.d[i]) ? a.d[i] : c.d[i];
  return r.v;
}

// ------- prep: pre-arrange B-fragments (bf16) into ws; one copy per block ------
// blocks 0..10 write copy 0, 11..21 copy 1, 22..32 copy 2 -> copies flow through
// different XCD L2s, so any single stale/corrupt path damages at most one copy.
__global__ void shq_prep(const float* __restrict__ qw, const float* __restrict__ rw,
                         unsigned short* __restrict__ rwfrag,
                         unsigned short* __restrict__ qwfrag, int st) {
  const int cp = blockIdx.x / 11;                    // copy index 0..2
  const int g = (blockIdx.x % 11) * 256 + threadIdx.x;
  unsigned short* rwd = rwfrag + cp * st;
  unsigned short* qwd = qwfrag + cp * st;
  if (g < 2048) {                       // 16 s * 2 kh * 64 lanes
    int s = g >> 7, kh = (g >> 6) & 1, ln = g & 63;
    int k = kh * 16 + (ln & 15), h0 = (ln >> 4) * 8;
    us8 v;
#pragma unroll
    for (int e = 0; e < 8; ++e) v[e] = f2bf(rw[((h0 + e) * 32 + k) * 16 + s]);
    *(us8*)(rwd + g * 8) = v;
  } else if (g < 2560) {                // 16 s * 2 kh * 16 lanes
    int j = g - 2048;
    int s = j >> 5, kh = (j >> 4) & 1, ln = j & 15;
    int hc = kh * 16 + ln;
    us8 v;
#pragma unroll
    for (int e = 0; e < 8; ++e) v[e] = f2bf(qw[(e * 32 + hc) * 16 + s]);
    *(us8*)(qwd + j * 8) = v;
  }
}

// ---------------- main kernel: 512 threads = 16 batch rows ----------------
__global__ __launch_bounds__(512, 2) void shq_main(
    const float* __restrict__ x, const float* __restrict__ hq_g,
    const float* __restrict__ syn, const float* __restrict__ corr,
    const unsigned short* __restrict__ rwfrag,
    const unsigned short* __restrict__ qwfrag,
    const float* __restrict__ tau_g,
    float* __restrict__ out, int st) {
  // Time-multiplexed buffer:
  //   [barA, barB): hqT bf16 [s][b][h], strides s:640, b:40 shorts (20.5 KB)
  //   [barB, end):  nq   f32 [b][s][h], strides b:BST, s:SST floats (37.1 KB)
  __shared__ float smem[16 * BST];
  __shared__ float2 lds_pi[NB * 16];   // (prob, inv_norm) per (b,s)
  unsigned short* hqT = (unsigned short*)smem;

  const int tid = threadIdx.x;
  const int b0 = blockIdx.x * NB;
  const int lane = tid & 63;
  const int w = tid >> 6;     // wave id: owns s = 2w, 2w+1
  const int kb = lane & 15;
  const int h0g = (lane >> 4) * 8;

  us8 z8 = {0, 0, 0, 0, 0, 0, 0, 0};

  // ---- prologue: x row + voted weight fragments + diag from tau ----
  us8 xu = z8;
  if (lane < 16) {
    const float* xb = x + (size_t)(b0 + lane) * 8;
    f32x4 a = *(const f32x4*)xb, b = *(const f32x4*)(xb + 4);
    xu[0] = f2bf(a[0]); xu[1] = f2bf(a[1]); xu[2] = f2bf(a[2]); xu[3] = f2bf(a[3]);
    xu[4] = f2bf(b[0]); xu[5] = f2bf(b[1]); xu[6] = f2bf(b[2]); xu[7] = f2bf(b[3]);
  }
  us8 rwf[2][2], qwf[2][2];
#pragma unroll
  for (int sl = 0; sl < 2; ++sl)
#pragma unroll
    for (int kh = 0; kh < 2; ++kh) {
      int s = 2 * w + sl;
      rwf[sl][kh] = ld2v(rwfrag + ((s * 2 + kh) * 64 + lane) * 8, st);
      qwf[sl][kh] = (lane < 16) ? ld2v(qwfrag + ((s * 2 + kh) * 16 + lane) * 8, st) : z8;
    }
  us8 dg0 = z8, dg1 = z8;
  {
    unsigned short v0 = f2bf(1.0f - 0.1f / tau_g[kb]);
    unsigned short v1 = f2bf(1.0f - 0.1f / tau_g[16 + kb]);
#pragma unroll
    for (int e = 0; e < 8; ++e) {
      dg0[e] = (h0g + e == kb) ? v0 : (unsigned short)0;
      dg1[e] = (h0g + e == 16 + kb) ? v1 : (unsigned short)0;
    }
  }

  // ---- phase 1: thread=(bl,h): syndrome -> mask -> correction -> hqT ----
  {
    const int bl = tid >> 5, hh = tid & 31;
    const float* hb = hq_g + (((size_t)(b0 + bl) * 32) + hh) * 16;
    f32x4 h0 = *(const f32x4*)(hb), h1 = *(const f32x4*)(hb + 4);
    f32x4 h2 = *(const f32x4*)(hb + 8), h3 = *(const f32x4*)(hb + 12);
    float hrow[16];
#pragma unroll
    for (int q = 0; q < 4; ++q) {
      hrow[0 + q] = h0[q]; hrow[4 + q] = h1[q]; hrow[8 + q] = h2[q]; hrow[12 + q] = h3[q];
    }
    float sd[4];
#pragma unroll
    for (int c = 0; c < 4; ++c) {
      float a = 0.f;
#pragma unroll
      for (int s = 0; s < 16; ++s) a = fmaf(hrow[s], syn[c * 16 + s], a);
      sd[c] = (fabsf(a) > 0.01f) ? a : 0.f;
    }
#pragma unroll
    for (int s = 0; s < 16; ++s) {
      float cs = sd[0] * corr[s] + sd[1] * corr[16 + s] + sd[2] * corr[32 + s] + sd[3] * corr[48 + s];
      hqT[s * 640 + bl * 40 + hh] = f2bf(hrow[s] - cs);
    }
  }
  __syncthreads();   // A: hqT ready

  // ---- phase 2a: pull A-frags (hq) out of hqT before it is clobbered ----
  us8 hq_u[2];
#pragma unroll
  for (int sl = 0; sl < 2; ++sl)
    hq_u[sl] = *(const us8*)&hqT[(2 * w + sl) * 640 + (lane & 15) * 40 + (lane >> 4) * 8];
  __syncthreads();   // B: hqT dead, nq region free

  // ---- phase 2b: MFMA rec+inp+decay per (s, khalf); write new_q f32 ----
  {
    f32x4 zro = {0.f, 0.f, 0.f, 0.f};
#pragma unroll
    for (int sl = 0; sl < 2; ++sl) {
      int s = 2 * w + sl;
      bf16x8 hqf = as_bf(hq_u[sl]);
#pragma unroll
      for (int kh = 0; kh < 2; ++kh) {
        f32x4 acc = __builtin_amdgcn_mfma_f32_16x16x32_bf16(as_bf(xu), as_bf(qwf[sl][kh]), zro, 0, 0, 0);
        acc = __builtin_amdgcn_mfma_f32_16x16x32_bf16(hqf, as_bf(rwf[sl][kh]), acc, 0, 0, 0);
        f32x4 na;
#pragma unroll
        for (int r = 0; r < 4; ++r) na[r] = tanh01(acc[r]);
        na = __builtin_amdgcn_mfma_f32_16x16x32_bf16(hqf, as_bf(kh ? dg1 : dg0), na, 0, 0, 0);
        int k = kh * 16 + (lane & 15);
#pragma unroll
        for (int r = 0; r < 4; ++r) {
          int br = (lane >> 4) * 4 + r;
          smem[br * BST + s * SST + k] = na[r];
        }
      }
    }
  }
  __syncthreads();   // C: nq ready

  // ---- phase 3a: thread=(b,s,half): stream stable, reduce norms, write pi ----
  {
    int b3 = tid >> 5, idx = tid & 31;
    int s3 = idx >> 1, half = idx & 1;
    int base = b3 * BST + s3 * SST + half * 16;
    float ssq = 0.f, sab = 0.f;
    f32x4 zv = {0.f, 0.f, 0.f, 0.f};
#pragma unroll
    for (int q = 0; q < 4; ++q) {
      f32x4 c0 = *(const f32x4*)&smem[base + 4 * q];
      f32x4 cm = (s3 > 0)  ? *(const f32x4*)&smem[base - SST + 4 * q] : zv;
      f32x4 cp = (s3 < 15) ? *(const f32x4*)&smem[base + SST + 4 * q] : zv;
#pragma unroll
      for (int e = 0; e < 4; ++e) {
        float st2 = fmaf(0.04f * c0[e], cm[e] + cp[e], c0[e]);
        ssq = fmaf(st2, st2, ssq);
        sab += fabsf(st2);
      }
    }
    ssq += __shfl_xor(ssq, 1);
    sab += __shfl_xor(sab, 1);
    float inv = __fdividef(1.0f, sqrtf(ssq) + 1e-8f);
    float energy = ssq * inv * inv;
    float mag = sab * inv;
    float pu = __fdividef(mag, energy + 1e-6f);
    float psum = pu;
#pragma unroll
    for (int m = 2; m < 32; m <<= 1) psum += __shfl_xor(psum, m);
    if (half == 0) {
      float2 pv = {__fdividef(pu, psum), inv};
      lds_pi[b3 * 16 + s3] = pv;
    }
  }
  __syncthreads();   // D: pi ready (nq untouched)

  // ---- phase 3b: thread=(b,h): streaming stable column, q_norm + output ----
  {
    const int b3 = tid >> 5, h3 = tid & 31;
    const float* colp = smem + b3 * BST + h3;
    float* qp = out + 4194304 + (((size_t)(b0 + b3) * 32) + h3) * 16;
    float prev = 0.f;
    float cur = colp[0];
    float oacc = 0.f;
    f32x4 qbuf;
#pragma unroll
    for (int s = 0; s < 16; ++s) {
      float nxt = (s < 15) ? colp[(s + 1) * SST] : 0.f;
      float st2 = fmaf(0.04f * cur, prev + nxt, cur);
      float2 pv = lds_pi[b3 * 16 + s];
      float q = st2 * pv.y;
      qbuf[s & 3] = q;
      oacc = fmaf(q, pv.x, oacc);
      if ((s & 3) == 3) *(f32x4*)(qp + (s - 3)) = qbuf;
      prev = cur; cur = nxt;
    }
    out[(size_t)(b0 + b3) * 32 + h3] = oacc;
  }
}

extern "C" void kernel_launch(void* const* d_in, const int* in_sizes, int n_in,
                              void* d_out, int out_size, void* d_ws, size_t ws_size,
                              hipStream_t stream) {
  const float* x    = (const float*)d_in[0];
  const float* hq   = (const float*)d_in[1];
  const float* qw   = (const float*)d_in[2];
  const float* rw   = (const float*)d_in[3];
  const float* tau  = (const float*)d_in[4];
  const float* syn  = (const float*)d_in[5];
  const float* corr = (const float*)d_in[6];
  unsigned short* ws = (unsigned short*)d_ws;
  unsigned short* rwfrag = ws;            // 16384 shorts
  unsigned short* qwfrag = ws + 16384;    // 4096 shorts (block ends at 20480)
  // triple-redundant copies at +st, +2*st shorts when ws allows (graph-safe const)
  const int st = (ws_size >= (size_t)300 * 1024) ? 24576 : 0;
  shq_prep<<<33, 256, 0, stream>>>(qw, rw, rwfrag, qwfrag, st);
  shq_main<<<B_TOTAL / NB, 512, 0, stream>>>(x, hq, syn, corr, rwfrag, qwfrag, tau, (float*)d_out, st);
}